// Round 5
// baseline (510.611 us; speedup 1.0000x reference)
//
#include <hip/hip_runtime.h>

// SNN forward: x[B,1,28,28] -> [T=28,B,28] -> Linear(28,32) -> IF
// -> Linear(32,10) -> IF -> mean spikes over T.
//
// Round-5: occupancy for latency hiding.
//  r4 was latency-bound (VALUBusy 28%, occ 27%): 1-row lookahead (~224 cyc
//  compute) vs ~900 cyc HBM latency, and the 40 KB byte-pair LUT capped us
//  at 3 blocks/CU while VGPR=76 allows 6 waves/SIMD. Fix:
//  * Drop byte-pair LUT; layer-2 uses the 5 KB nibble LUT (exact r1
//    arithmetic -> absmax 0.0). LDS ~9 KB/block.
//  * __launch_bounds__(256,6): 6 blocks/CU = 24 waves/CU; 5 co-resident
//    waves/SIMD x 224 cyc compute > 900 cyc HBM latency -> stalls hidden.
//  * Flat grid (4096 blocks, no grid-stride) so blocks retire/refill.
//  Unchanged from r4 (the spill-proof structure): 16 lanes/sample,
//  2 neurons/lane, rolled ping-pong i-loop (14 float4 in flight, all
//  register arrays constant-indexed), W1 in LDS padded [32][29].

#define THREADS 256
#define SPB     16    // samples per block (4/wave x 4 waves)

__global__ __launch_bounds__(THREADS, 6) void snn_if_kernel(
    const float* __restrict__ x,    // [B][28][28]  (b, i, t) t fastest
    const float* __restrict__ W1,   // [32][28]
    const float* __restrict__ b1,   // [32]
    const float* __restrict__ W2,   // [10][32]
    const float* __restrict__ b2,   // [10]
    float* __restrict__ out,        // [B][10]
    int B)
{
    __shared__ float Ws[32 * 29];   // W1 padded stride 29 (conflict-free)
    __shared__ float T4[1280];      // nibble tables [k<8][nib<16][o2<10]

    const int tid = threadIdx.x;
    const int p   = tid & 15;         // lane owns neurons o=p and o=p+16
    const int g16 = (tid & 63) >> 4;  // 16-lane sample group within wave
    const int sl  = tid >> 4;         // sample slot within block 0..15

    // ---- W1 -> LDS (padded) ----
    for (int e = tid; e < 32 * 28; e += THREADS) {
        int o = e / 28, i = e - o * 28;
        Ws[o * 29 + i] = W1[e];
    }
    // ---- nibble tables (exact r1 arithmetic) ----
    for (int e = tid; e < 1280; e += THREADS) {
        int o2 = e % 10;
        int tn = e / 10;
        int nb = tn & 15, k = tn >> 4;
        float v = 0.f;
        if (nb & 1) v += W2[o2 * 32 + 4 * k + 0];
        if (nb & 2) v += W2[o2 * 32 + 4 * k + 1];
        if (nb & 4) v += W2[o2 * 32 + 4 * k + 2];
        if (nb & 8) v += W2[o2 * 32 + 4 * k + 3];
        T4[e] = v;
    }

    const float b1a = b1[p];
    const float b1b = b1[p + 16];
    const float b2o = (p < 10) ? b2[p] : 0.f;
    __syncthreads();

    int samp = blockIdx.x * SPB + sl;
    bool ok  = (samp < B);
    const float* xs = x + (size_t)(ok ? samp : 0) * 784;

    float accA[28], accB[28];
    #pragma unroll
    for (int t = 0; t < 28; ++t) { accA[t] = 0.f; accB[t] = 0.f; }

    float4 c[7], n[7];
    {
        const float4* r0 = (const float4*)xs;       // row 0
        #pragma unroll
        for (int q = 0; q < 7; ++q) c[q] = r0[q];
    }

    // acc[t] += W1[o][i] * x[i][t], i ascending; ping-pong 1-row lookahead
    #pragma unroll 1
    for (int i = 0; i < 28; i += 2) {
        const float4* rn = (const float4*)(xs + (i + 1) * 28);  // row i+1
        #pragma unroll
        for (int q = 0; q < 7; ++q) n[q] = rn[q];
        float wA = Ws[p * 29 + i];
        float wB = Ws[(p + 16) * 29 + i];
        #pragma unroll
        for (int q = 0; q < 7; ++q) {
            accA[4*q+0] = fmaf(wA, c[q].x, accA[4*q+0]);
            accA[4*q+1] = fmaf(wA, c[q].y, accA[4*q+1]);
            accA[4*q+2] = fmaf(wA, c[q].z, accA[4*q+2]);
            accA[4*q+3] = fmaf(wA, c[q].w, accA[4*q+3]);
            accB[4*q+0] = fmaf(wB, c[q].x, accB[4*q+0]);
            accB[4*q+1] = fmaf(wB, c[q].y, accB[4*q+1]);
            accB[4*q+2] = fmaf(wB, c[q].z, accB[4*q+2]);
            accB[4*q+3] = fmaf(wB, c[q].w, accB[4*q+3]);
        }
        const float4* rc = (const float4*)(xs + (i + 2 < 28 ? i + 2 : 0) * 28);
        #pragma unroll
        for (int q = 0; q < 7; ++q) c[q] = rc[q];    // row for next even i
        float wA1 = Ws[p * 29 + i + 1];
        float wB1 = Ws[(p + 16) * 29 + i + 1];
        #pragma unroll
        for (int q = 0; q < 7; ++q) {
            accA[4*q+0] = fmaf(wA1, n[q].x, accA[4*q+0]);
            accA[4*q+1] = fmaf(wA1, n[q].y, accA[4*q+1]);
            accA[4*q+2] = fmaf(wA1, n[q].z, accA[4*q+2]);
            accA[4*q+3] = fmaf(wA1, n[q].w, accA[4*q+3]);
            accB[4*q+0] = fmaf(wB1, n[q].x, accB[4*q+0]);
            accB[4*q+1] = fmaf(wB1, n[q].y, accB[4*q+1]);
            accB[4*q+2] = fmaf(wB1, n[q].z, accB[4*q+2]);
            accB[4*q+3] = fmaf(wB1, n[q].w, accB[4*q+3]);
        }
    }

    // ---- sequential IF scan fused with layer 2 (nibble LUT, r1 order) ----
    float v1a = 0.f, v1b = 0.f, v2 = 0.f, cnt = 0.f;
    #pragma unroll
    for (int t = 0; t < 28; ++t) {
        v1a += accA[t] + b1a;                  // neurons 0..15
        v1b += accB[t] + b1b;                  // neurons 16..31
        bool sA = (v1a >= 1.0f);
        bool sB = (v1b >= 1.0f);
        unsigned long long balA = __ballot(sA);
        unsigned long long balB = __ballot(sB);
        if (sA) v1a = 0.f;                     // hard reset
        if (sB) v1b = 0.f;
        unsigned mlo = (unsigned)(balA >> (g16 * 16)) & 0xFFFFu;
        unsigned mhi = (unsigned)(balB >> (g16 * 16)) & 0xFFFFu;
        unsigned m = mlo | (mhi << 16);        // bit i = spike of neuron i

        if (p < 10) {
            float a2 = 0.f;
            #pragma unroll
            for (int k = 0; k < 8; ++k) {
                unsigned nib = (m >> (4 * k)) & 15u;
                a2 += T4[k * 160 + nib * 10 + p];
            }
            v2 += a2 + b2o;
            if (v2 >= 1.0f) { cnt += 1.f; v2 = 0.f; }
        }
    }

    if (p < 10 && ok) {
        out[(size_t)samp * 10 + p] = cnt / 28.0f;
    }
}

extern "C" void kernel_launch(void* const* d_in, const int* in_sizes, int n_in,
                              void* d_out, int out_size, void* d_ws, size_t ws_size,
                              hipStream_t stream) {
    const float* x  = (const float*)d_in[0];
    const float* W1 = (const float*)d_in[1];
    const float* b1 = (const float*)d_in[2];
    const float* W2 = (const float*)d_in[3];
    const float* b2 = (const float*)d_in[4];
    float* out = (float*)d_out;

    int B = in_sizes[0] / 784;               // 65536
    int grid = (B + SPB - 1) / SPB;          // 4096
    snn_if_kernel<<<grid, THREADS, 0, stream>>>(x, W1, b1, W2, b2, out, B);
}

// Round 6
// 491.349 us; speedup vs baseline: 1.0392x; 1.0392x over previous
//
#include <hip/hip_runtime.h>

// SNN forward: x[B,1,28,28] -> [T=28,B,28] -> Linear(28,32) -> IF
// -> Linear(32,10) -> IF -> mean spikes over T.
//
// Round-6: r5 structure with the register cap RELAXED.
//  r5 post-mortem: __launch_bounds__(256,6) (cap 85) forced the allocator
//  under the ~90-100 VGPR working set (accA/accB=56 + 14-float4 pipeline)
//  -> VGPR=40 + scratch (WRITE_SIZE 2.5->30 MB), dur 310 us. Occupancy is
//  set by ACTUAL VGPR use: r4's identical loop compiled to 76 VGPR under a
//  loose cap, and 76 natively allows 6 waves/SIMD. With LDS at 9 KB the
//  hardware reaches 6 blocks/CU = 24 waves/CU with NO forced cap.
//  Only change vs r5: __launch_bounds__(256,4) (cap 128).
//  Latency budget: 5 co-resident waves x ~224 cyc compute per 7-load batch
//  ~ 1120 cyc > ~900 cyc HBM miss latency -> stalls hidden.

#define THREADS 256
#define SPB     16    // samples per block (4/wave x 4 waves)

__global__ __launch_bounds__(THREADS, 4) void snn_if_kernel(
    const float* __restrict__ x,    // [B][28][28]  (b, i, t) t fastest
    const float* __restrict__ W1,   // [32][28]
    const float* __restrict__ b1,   // [32]
    const float* __restrict__ W2,   // [10][32]
    const float* __restrict__ b2,   // [10]
    float* __restrict__ out,        // [B][10]
    int B)
{
    __shared__ float Ws[32 * 29];   // W1 padded stride 29 (conflict-free)
    __shared__ float T4[1280];      // nibble tables [k<8][nib<16][o2<10]

    const int tid = threadIdx.x;
    const int p   = tid & 15;         // lane owns neurons o=p and o=p+16
    const int g16 = (tid & 63) >> 4;  // 16-lane sample group within wave
    const int sl  = tid >> 4;         // sample slot within block 0..15

    // ---- W1 -> LDS (padded) ----
    for (int e = tid; e < 32 * 28; e += THREADS) {
        int o = e / 28, i = e - o * 28;
        Ws[o * 29 + i] = W1[e];
    }
    // ---- nibble tables (exact r1 arithmetic) ----
    for (int e = tid; e < 1280; e += THREADS) {
        int o2 = e % 10;
        int tn = e / 10;
        int nb = tn & 15, k = tn >> 4;
        float v = 0.f;
        if (nb & 1) v += W2[o2 * 32 + 4 * k + 0];
        if (nb & 2) v += W2[o2 * 32 + 4 * k + 1];
        if (nb & 4) v += W2[o2 * 32 + 4 * k + 2];
        if (nb & 8) v += W2[o2 * 32 + 4 * k + 3];
        T4[e] = v;
    }

    const float b1a = b1[p];
    const float b1b = b1[p + 16];
    const float b2o = (p < 10) ? b2[p] : 0.f;
    __syncthreads();

    int samp = blockIdx.x * SPB + sl;
    bool ok  = (samp < B);
    const float* xs = x + (size_t)(ok ? samp : 0) * 784;

    float accA[28], accB[28];
    #pragma unroll
    for (int t = 0; t < 28; ++t) { accA[t] = 0.f; accB[t] = 0.f; }

    float4 c[7], n[7];
    {
        const float4* r0 = (const float4*)xs;       // row 0
        #pragma unroll
        for (int q = 0; q < 7; ++q) c[q] = r0[q];
    }

    // acc[t] += W1[o][i] * x[i][t], i ascending; ping-pong 1-row lookahead
    #pragma unroll 1
    for (int i = 0; i < 28; i += 2) {
        const float4* rn = (const float4*)(xs + (i + 1) * 28);  // row i+1
        #pragma unroll
        for (int q = 0; q < 7; ++q) n[q] = rn[q];
        float wA = Ws[p * 29 + i];
        float wB = Ws[(p + 16) * 29 + i];
        #pragma unroll
        for (int q = 0; q < 7; ++q) {
            accA[4*q+0] = fmaf(wA, c[q].x, accA[4*q+0]);
            accA[4*q+1] = fmaf(wA, c[q].y, accA[4*q+1]);
            accA[4*q+2] = fmaf(wA, c[q].z, accA[4*q+2]);
            accA[4*q+3] = fmaf(wA, c[q].w, accA[4*q+3]);
            accB[4*q+0] = fmaf(wB, c[q].x, accB[4*q+0]);
            accB[4*q+1] = fmaf(wB, c[q].y, accB[4*q+1]);
            accB[4*q+2] = fmaf(wB, c[q].z, accB[4*q+2]);
            accB[4*q+3] = fmaf(wB, c[q].w, accB[4*q+3]);
        }
        const float4* rc = (const float4*)(xs + (i + 2 < 28 ? i + 2 : 0) * 28);
        #pragma unroll
        for (int q = 0; q < 7; ++q) c[q] = rc[q];    // row for next even i
        float wA1 = Ws[p * 29 + i + 1];
        float wB1 = Ws[(p + 16) * 29 + i + 1];
        #pragma unroll
        for (int q = 0; q < 7; ++q) {
            accA[4*q+0] = fmaf(wA1, n[q].x, accA[4*q+0]);
            accA[4*q+1] = fmaf(wA1, n[q].y, accA[4*q+1]);
            accA[4*q+2] = fmaf(wA1, n[q].z, accA[4*q+2]);
            accA[4*q+3] = fmaf(wA1, n[q].w, accA[4*q+3]);
            accB[4*q+0] = fmaf(wB1, n[q].x, accB[4*q+0]);
            accB[4*q+1] = fmaf(wB1, n[q].y, accB[4*q+1]);
            accB[4*q+2] = fmaf(wB1, n[q].z, accB[4*q+2]);
            accB[4*q+3] = fmaf(wB1, n[q].w, accB[4*q+3]);
        }
    }

    // ---- sequential IF scan fused with layer 2 (nibble LUT, r1 order) ----
    float v1a = 0.f, v1b = 0.f, v2 = 0.f, cnt = 0.f;
    #pragma unroll
    for (int t = 0; t < 28; ++t) {
        v1a += accA[t] + b1a;                  // neurons 0..15
        v1b += accB[t] + b1b;                  // neurons 16..31
        bool sA = (v1a >= 1.0f);
        bool sB = (v1b >= 1.0f);
        unsigned long long balA = __ballot(sA);
        unsigned long long balB = __ballot(sB);
        if (sA) v1a = 0.f;                     // hard reset
        if (sB) v1b = 0.f;
        unsigned mlo = (unsigned)(balA >> (g16 * 16)) & 0xFFFFu;
        unsigned mhi = (unsigned)(balB >> (g16 * 16)) & 0xFFFFu;
        unsigned m = mlo | (mhi << 16);        // bit i = spike of neuron i

        if (p < 10) {
            float a2 = 0.f;
            #pragma unroll
            for (int k = 0; k < 8; ++k) {
                unsigned nib = (m >> (4 * k)) & 15u;
                a2 += T4[k * 160 + nib * 10 + p];
            }
            v2 += a2 + b2o;
            if (v2 >= 1.0f) { cnt += 1.f; v2 = 0.f; }
        }
    }

    if (p < 10 && ok) {
        out[(size_t)samp * 10 + p] = cnt / 28.0f;
    }
}

extern "C" void kernel_launch(void* const* d_in, const int* in_sizes, int n_in,
                              void* d_out, int out_size, void* d_ws, size_t ws_size,
                              hipStream_t stream) {
    const float* x  = (const float*)d_in[0];
    const float* W1 = (const float*)d_in[1];
    const float* b1 = (const float*)d_in[2];
    const float* W2 = (const float*)d_in[3];
    const float* b2 = (const float*)d_in[4];
    float* out = (float*)d_out;

    int B = in_sizes[0] / 784;               // 65536
    int grid = (B + SPB - 1) / SPB;          // 4096
    snn_if_kernel<<<grid, THREADS, 0, stream>>>(x, W1, b1, W2, b2, out, B);
}